// Round 1
// baseline (2901.221 us; speedup 1.0000x reference)
//
#include <hip/hip_runtime.h>
#include <math.h>

// Problem constants
#define HH 128
#define WW 128
#define BB 2
#define CC 192
#define DG 4
#define KK 9
#define CKTOT (CC * KK)   // 1728
#define SLD 1732          // padded LDS row (1732 % 32 == 4 -> 2-way conflicts only)
#define TP 16             // pixels per block in fused kernel

// ---------------------------------------------------------------------------
// Generic 3x3 conv, pad 1, f32, NCHW. Input channels may come from two
// tensors (concat): channel cg < cin0 -> in0, else in1.
// Block: 256 threads, 32x32 spatial tile, 8 output channels, 2-ci LDS chunks.
// ---------------------------------------------------------------------------
__global__ __launch_bounds__(256) void conv3x3_k(
    const float* __restrict__ in0, const float* __restrict__ in1, int cin0,
    const float* __restrict__ w, const float* __restrict__ bias,
    float* __restrict__ out, int Cin, int Cout)
{
    __shared__ float tile[2][34 * 34];
    __shared__ float wl[2][8][9];

    const int t  = threadIdx.x;
    const int j0 = blockIdx.x * 32;
    const int i0 = blockIdx.y * 32;
    const int OG = (Cout + 7) >> 3;
    const int b  = blockIdx.z / OG;
    const int og = blockIdx.z % OG;
    const int jl = t & 31;        // 0..31
    const int il = t >> 5;        // 0..7 ; rows il + 8q

    float acc[8][4];
#pragma unroll
    for (int oo = 0; oo < 8; oo++)
#pragma unroll
        for (int q = 0; q < 4; q++) acc[oo][q] = 0.f;

    for (int cb = 0; cb < Cin; cb += 2) {
        __syncthreads();
        // stage 2 input channels (34x34 halo tile each)
        for (int ci = 0; ci < 2; ci++) {
            const int cg = cb + ci;
            const float* src;
            size_t cbase;
            if (cg < cin0) { src = in0; cbase = (size_t)(b * cin0 + cg) * (HH * WW); }
            else           { src = in1; cbase = (size_t)(b * (Cin - cin0) + (cg - cin0)) * (HH * WW); }
            for (int idx = t; idx < 34 * 34; idx += 256) {
                const int r  = idx / 34;
                const int cc = idx - r * 34;
                const int gy = i0 - 1 + r;
                const int gx = j0 - 1 + cc;
                float v = 0.f;
                if (gy >= 0 && gy < HH && gx >= 0 && gx < WW)
                    v = src[cbase + (size_t)gy * WW + gx];
                tile[ci][idx] = v;
            }
        }
        // stage weights: 8 outs x 2 ci x 9 taps = 144
        if (t < 144) {
            const int oo  = t / 18;
            const int rem = t - oo * 18;
            const int ci  = rem / 9;
            const int tap = rem - ci * 9;
            const int o   = og * 8 + oo;
            float v = 0.f;
            if (o < Cout) v = w[((size_t)o * Cin + (cb + ci)) * 9 + tap];
            wl[ci][oo][tap] = v;
        }
        __syncthreads();
        // compute
#pragma unroll
        for (int ci = 0; ci < 2; ci++) {
#pragma unroll
            for (int tap = 0; tap < 9; tap++) {
                const int dy = tap / 3, dx = tap % 3;
                const float t0 = tile[ci][(il + 0  + dy) * 34 + jl + dx];
                const float t1 = tile[ci][(il + 8  + dy) * 34 + jl + dx];
                const float t2 = tile[ci][(il + 16 + dy) * 34 + jl + dx];
                const float t3 = tile[ci][(il + 24 + dy) * 34 + jl + dx];
#pragma unroll
                for (int oo = 0; oo < 8; oo++) {
                    const float wv = wl[ci][oo][tap];
                    acc[oo][0] += wv * t0;
                    acc[oo][1] += wv * t1;
                    acc[oo][2] += wv * t2;
                    acc[oo][3] += wv * t3;
                }
            }
        }
    }
    // store
#pragma unroll
    for (int oo = 0; oo < 8; oo++) {
        const int o = og * 8 + oo;
        if (o < Cout) {
            const float bv = bias[o];
#pragma unroll
            for (int q = 0; q < 4; q++) {
                const int iy = i0 + il + 8 * q;
                out[(((size_t)b * Cout + o) * HH + iy) * WW + j0 + jl] = acc[oo][q] + bv;
            }
        }
    }
}

// ---------------------------------------------------------------------------
// Fused deform-sample + einsum. One block per (b, row i, 16 pixels).
// Phase A1: 36*(g,k) x 16 px bilinear entries (offsets, sigmoid mask).
// Phase A2: S[p][c*9+k] = masked bilinear sample of x_vq.
// Phase B : y[o][p] = b_dcn[o] + sum_ck wd[o][ck] * S[p][ck].
// ---------------------------------------------------------------------------
__global__ __launch_bounds__(256) void dcn_fuse_k(
    const float* __restrict__ x,    // x_vq  B x 192 x 128 x 128
    const float* __restrict__ off,  // B x 108 x 128 x 128 (raw conv output)
    const float* __restrict__ wd,   // 192 x 1728
    const float* __restrict__ bd,   // 192
    float* __restrict__ out)        // B x 192 x 128 x 128
{
    __shared__ __align__(16) float S[TP][SLD];
    __shared__ float eW[4][DG * KK * TP];
    __shared__ int   eY[DG * KK * TP];
    __shared__ int   eX[DG * KK * TP];

    const int t  = threadIdx.x;
    const int b  = blockIdx.z;
    const int i  = blockIdx.y;
    const int j0 = blockIdx.x * TP;

    // ---- Phase A1: entries --------------------------------------------------
    for (int e = t; e < DG * KK * TP; e += 256) {
        const int p  = e & (TP - 1);
        const int gk = e >> 4;                 // g*9+k
        const int k  = gk % 9;
        const int j  = j0 + p;
        const size_t sp = (size_t)b * 108 * (HH * WW) + (size_t)gk * (HH * WW) + (size_t)i * WW + j;
        const float dy = off[sp];
        const float dx = off[sp + (size_t)36 * (HH * WW)];
        const float mv = off[sp + (size_t)72 * (HH * WW)];
        const float m  = 1.f / (1.f + expf(-mv));
        const float ky = (float)(k / 3 - 1);
        const float kx = (float)(k % 3 - 1);
        const float py = (float)i + ky + dy;
        const float px = (float)j + kx + dx;
        const float y0f = floorf(py), x0f = floorf(px);
        const float ly = py - y0f, lx = px - x0f;
        const int y0 = (int)y0f, x0 = (int)x0f;
        const float vy0 = (y0 >= 0 && y0 < HH) ? 1.f : 0.f;
        const float vy1 = (y0 + 1 >= 0 && y0 + 1 < HH) ? 1.f : 0.f;
        const float vx0 = (x0 >= 0 && x0 < WW) ? 1.f : 0.f;
        const float vx1 = (x0 + 1 >= 0 && x0 + 1 < WW) ? 1.f : 0.f;
        eY[e] = y0; eX[e] = x0;
        eW[0][e] = (1.f - ly) * (1.f - lx) * m * vy0 * vx0;
        eW[1][e] = (1.f - ly) * lx         * m * vy0 * vx1;
        eW[2][e] = ly         * (1.f - lx) * m * vy1 * vx0;
        eW[3][e] = ly         * lx         * m * vy1 * vx1;
    }
    __syncthreads();

    // ---- Phase A2: samples --------------------------------------------------
    for (int it = t; it < TP * CKTOT; it += 256) {
        const int p  = it / CKTOT;
        const int ck = it - p * CKTOT;
        const int c  = ck / 9;
        const int k  = ck - c * 9;
        const int g  = c / 48;
        const int e  = (g * 9 + k) * TP + p;
        const int y0 = eY[e], x0 = eX[e];
        const int yc0 = min(max(y0, 0), HH - 1);
        const int yc1 = min(max(y0 + 1, 0), HH - 1);
        const int xc0 = min(max(x0, 0), WW - 1);
        const int xc1 = min(max(x0 + 1, 0), WW - 1);
        const float* xb = x + (((size_t)b * CC + c) << 14);
        const float v00 = xb[(yc0 << 7) + xc0];
        const float v01 = xb[(yc0 << 7) + xc1];
        const float v10 = xb[(yc1 << 7) + xc0];
        const float v11 = xb[(yc1 << 7) + xc1];
        S[p][ck] = eW[0][e] * v00 + eW[1][e] * v01 + eW[2][e] * v10 + eW[3][e] * v11;
    }
    __syncthreads();

    // ---- Phase B: 192 x 1728 matvec for 16 pixels ---------------------------
    const int p  = t & (TP - 1);
    const int ob = t >> 4;   // 0..15
    float acc[12];
#pragma unroll
    for (int r = 0; r < 12; r++) acc[r] = 0.f;

    for (int ck4 = 0; ck4 < CKTOT / 4; ck4++) {
        const float4 s4 = *(const float4*)&S[p][ck4 * 4];
#pragma unroll
        for (int r = 0; r < 12; r++) {
            const int o = ob + 16 * r;
            const float4 wv = *(const float4*)&wd[(size_t)o * CKTOT + ck4 * 4];
            acc[r] += wv.x * s4.x + wv.y * s4.y + wv.z * s4.z + wv.w * s4.w;
        }
    }
#pragma unroll
    for (int r = 0; r < 12; r++) {
        const int o = ob + 16 * r;
        out[(((size_t)b * CC + o) << 14) + (i << 7) + j0 + p] = acc[r] + bd[o];
    }
}

// ---------------------------------------------------------------------------
extern "C" void kernel_launch(void* const* d_in, const int* in_sizes, int n_in,
                              void* d_out, int out_size, void* d_ws, size_t ws_size,
                              hipStream_t stream)
{
    const float* x_vq  = (const float*)d_in[0];
    const float* x_res = (const float*)d_in[1];
    const float* w_off = (const float*)d_in[2];
    const float* b_off = (const float*)d_in[3];
    const float* w_co  = (const float*)d_in[4];
    const float* b_co  = (const float*)d_in[5];
    const float* w_dcn = (const float*)d_in[6];
    const float* b_dcn = (const float*)d_in[7];
    float* out = (float*)d_out;

    float* feat = (float*)d_ws;                              // 2*192*16384 f32 = 25.2 MB
    float* offb = feat + (size_t)BB * CC * HH * WW;          // 2*108*16384 f32 = 14.2 MB

    dim3 blk(256);
    // conv1: concat(x_vq, x_res) [384ch] -> feat [192ch]
    conv3x3_k<<<dim3(4, 4, BB * 24), blk, 0, stream>>>(
        x_vq, x_res, 192, w_off, b_off, feat, 384, 192);
    // conv2: feat [192ch] -> off [108ch]
    conv3x3_k<<<dim3(4, 4, BB * 14), blk, 0, stream>>>(
        feat, nullptr, 192, w_co, b_co, offb, 192, 108);
    // fused deform sample + einsum
    dcn_fuse_k<<<dim3(WW / TP, HH, BB), blk, 0, stream>>>(
        x_vq, offb, w_dcn, b_dcn, out);
}

// Round 2
// 620.540 us; speedup vs baseline: 4.6753x; 4.6753x over previous
//
#include <hip/hip_runtime.h>
#include <math.h>

#define HH 128
#define WW 128
#define HW 16384
#define BB 2
#define CC 192
#define DG 4
#define KK 9

typedef __attribute__((ext_vector_type(8))) short short8;
typedef __attribute__((ext_vector_type(4))) float f32x4;

// f32 -> bf16 bits, round-to-nearest-even (finite inputs)
static __device__ __forceinline__ short f2bf(float f) {
    unsigned u = __float_as_uint(f);
    unsigned r = (u + 0x7FFFu + ((u >> 16) & 1u)) >> 16;
    return (short)r;
}

// ---------------------------------------------------------------------------
// Pack f32 weight matrix [Co][K] into MFMA A-frag order:
// wp[((mt*NQ + q)*64 + lane)*8 + r] = bf16(w[o=mt*16+(lane&15)][k=q*32+(lane>>4)*8+r])
// Zero-pad o >= Co. K must be a multiple of 32.
// ---------------------------------------------------------------------------
__global__ void pack_w_k(const float* __restrict__ w, short* __restrict__ wp,
                         int Co, int K, int MT, int NQ)
{
    int idx = blockIdx.x * blockDim.x + threadIdx.x;   // one per (mt,q,lane)
    int total = MT * NQ * 64;
    if (idx >= total) return;
    const int l  = idx & 63;
    const int mq = idx >> 6;
    const int q  = mq % NQ;
    const int mt = mq / NQ;
    const int o  = mt * 16 + (l & 15);
    const int kg = q * 32 + ((l >> 4) << 3);
    short8 v;
#pragma unroll
    for (int r = 0; r < 8; r++) {
        float f = (o < Co) ? w[(size_t)o * K + kg + r] : 0.f;
        v[r] = f2bf(f);
    }
    *reinterpret_cast<short8*>(wp + (size_t)idx * 8) = v;
}

// ---------------------------------------------------------------------------
// Implicit-GEMM 3x3 conv (pad 1), bf16 MFMA. Block = 512 thr (8 waves),
// out tile [Cout up to MR*64][64 px] for one (b, row i). Wave (wo=wid>>1,
// wp=wid&1) owns m-tiles wo*MR..wo*MR+MR-1 and px half wp*32..+31.
// B-tile (im2col chunk [32 ck][64 px]) built in LDS in B-frag order.
// ---------------------------------------------------------------------------
template<int MR, bool CONCAT, typename InT, typename OutT>
__global__ __launch_bounds__(512) void conv_mfma_k(
    const InT* __restrict__ in0, const InT* __restrict__ in1,
    const short* __restrict__ wA, const float* __restrict__ bias,
    OutT* __restrict__ out, int Cin, int Cout, int NQ)
{
    __shared__ __align__(16) short SB[4][64][8];

    const int t    = threadIdx.x;
    const int lane = t & 63;
    const int wid  = t >> 6;
    const int wo   = wid >> 1;
    const int wp   = wid & 1;
    const int j0   = blockIdx.x * 64;
    const int i    = blockIdx.y;
    const int b    = blockIdx.z;
    const int pp   = t >> 3;   // staging pixel 0..63
    const int k7   = t & 7;    // staging k sub-index

    f32x4 acc[MR][2];
#pragma unroll
    for (int rr = 0; rr < MR; rr++) {
        acc[rr][0] = (f32x4){0.f, 0.f, 0.f, 0.f};
        acc[rr][1] = (f32x4){0.f, 0.f, 0.f, 0.f};
    }

    for (int q = 0; q < NQ; q++) {
        short8 aF[MR];
#pragma unroll
        for (int rr = 0; rr < MR; rr++)
            aF[rr] = *reinterpret_cast<const short8*>(
                wA + ((size_t)((wo * MR + rr) * NQ + q) * 64 + lane) * 8);

        __syncthreads();   // previous chunk's reads done
#pragma unroll
        for (int it = 0; it < 4; it++) {
            const int kl = it * 8 + k7;
            const unsigned ck = q * 32 + kl;
            const unsigned ci = ck / 9u;
            const int tap = (int)(ck - ci * 9u);
            const int iy = i + tap / 3 - 1;
            const int jx = j0 + pp + (tap % 3) - 1;
            short bits = 0;
            if (iy >= 0 && iy < HH && jx >= 0 && jx < WW) {
                const InT* src;
                size_t ofs;
                if constexpr (CONCAT) {
                    const int half = Cin / 2;
                    if ((int)ci < half) { src = in0; ofs = (size_t)(b * half + ci) << 14; }
                    else                { src = in1; ofs = (size_t)(b * half + (int)ci - half) << 14; }
                } else {
                    src = in0; ofs = (size_t)(b * Cin + ci) << 14;
                }
                if constexpr (sizeof(InT) == 2) bits = (short)src[ofs + (iy << 7) + jx];
                else                            bits = f2bf((float)src[ofs + (iy << 7) + jx]);
            }
            SB[pp >> 4][(pp & 15) + 16 * it][k7] = bits;
        }
        __syncthreads();

        const short8 bF0 = *reinterpret_cast<const short8*>(&SB[wp * 2 + 0][lane][0]);
        const short8 bF1 = *reinterpret_cast<const short8*>(&SB[wp * 2 + 1][lane][0]);
#pragma unroll
        for (int rr = 0; rr < MR; rr++) {
            acc[rr][0] = __builtin_amdgcn_mfma_f32_16x16x32_bf16(aF[rr], bF0, acc[rr][0], 0, 0, 0);
            acc[rr][1] = __builtin_amdgcn_mfma_f32_16x16x32_bf16(aF[rr], bF1, acc[rr][1], 0, 0, 0);
        }
    }

    // store: C/D layout n=lane&15, m=(lane>>4)*4+jr  [m89-verified]
    const int n0 = lane & 15;
    const int m4 = (lane >> 4) << 2;
#pragma unroll
    for (int rr = 0; rr < MR; rr++) {
#pragma unroll
        for (int nn = 0; nn < 2; nn++) {
            const int px = wp * 32 + nn * 16 + n0;
#pragma unroll
            for (int jr = 0; jr < 4; jr++) {
                const int o = (wo * MR + rr) * 16 + m4 + jr;
                if (o < Cout) {
                    const float v = acc[rr][nn][jr] + bias[o];
                    if constexpr (sizeof(OutT) == 2)
                        out[((size_t)(b * Cout + o) << 14) + (i << 7) + j0 + px] = (OutT)f2bf(v);
                    else
                        out[((size_t)(b * Cout + o) << 14) + (i << 7) + j0 + px] = (OutT)v;
                }
            }
        }
    }
}

// ---------------------------------------------------------------------------
// Fused deform-sample + einsum, bf16 MFMA. Block = 512 thr, out [192][64 px]
// per (b,i). Phase A1 precomputes 36x64 bilinear entries (mask folded into
// weights); K-loop gathers the [32 ck][64 px] B-tile directly into frag order.
// ---------------------------------------------------------------------------
__global__ __launch_bounds__(512) void dcn_mfma_k(
    const float* __restrict__ x, const float* __restrict__ off,
    const short* __restrict__ wA, const float* __restrict__ bias,
    float* __restrict__ out)
{
    __shared__ __align__(16) f32x4 eW4[DG * KK * 64];   // 36 KB
    __shared__ int eXY[DG * KK * 64];                    // 9 KB
    __shared__ __align__(16) short SB[4][64][8];         // 4 KB

    const int t    = threadIdx.x;
    const int lane = t & 63;
    const int wid  = t >> 6;
    const int wo   = wid >> 1;
    const int wp   = wid & 1;
    const int j0   = blockIdx.x * 64;
    const int i    = blockIdx.y;
    const int b    = blockIdx.z;
    const int pp   = t >> 3;
    const int k7   = t & 7;

    // ---- Phase A1: bilinear entries -------------------------------------
    for (int e = t; e < DG * KK * 64; e += 512) {
        const int p  = e & 63;
        const int gk = e >> 6;              // g*9+k
        const int kt = gk % 9;
        const int j  = j0 + p;
        const size_t sp = (size_t)b * 108 * HW + (size_t)gk * HW + (i << 7) + j;
        const float dy = off[sp];
        const float dx = off[sp + (size_t)36 * HW];
        const float mv = off[sp + (size_t)72 * HW];
        const float m  = 1.f / (1.f + expf(-mv));
        const float py = (float)(i + kt / 3 - 1) + dy;
        const float px = (float)(j + kt % 3 - 1) + dx;
        const float y0f = floorf(py), x0f = floorf(px);
        const float ly = py - y0f, lx = px - x0f;
        const int y0 = (int)y0f, x0 = (int)x0f;
        const float vy0 = (y0 >= 0 && y0 < HH) ? 1.f : 0.f;
        const float vy1 = (y0 + 1 >= 0 && y0 + 1 < HH) ? 1.f : 0.f;
        const float vx0 = (x0 >= 0 && x0 < WW) ? 1.f : 0.f;
        const float vx1 = (x0 + 1 >= 0 && x0 + 1 < WW) ? 1.f : 0.f;
        f32x4 w4;
        w4[0] = (1.f - ly) * (1.f - lx) * m * vy0 * vx0;
        w4[1] = (1.f - ly) * lx         * m * vy0 * vx1;
        w4[2] = ly         * (1.f - lx) * m * vy1 * vx0;
        w4[3] = ly         * lx         * m * vy1 * vx1;
        eW4[e] = w4;
        eXY[e] = (y0 << 16) | (x0 & 0xFFFF);
    }

    f32x4 acc[3][2];
#pragma unroll
    for (int rr = 0; rr < 3; rr++) {
        acc[rr][0] = (f32x4){0.f, 0.f, 0.f, 0.f};
        acc[rr][1] = (f32x4){0.f, 0.f, 0.f, 0.f};
    }

    const int NQ = 54;
    for (int q = 0; q < NQ; q++) {
        short8 aF[3];
#pragma unroll
        for (int rr = 0; rr < 3; rr++)
            aF[rr] = *reinterpret_cast<const short8*>(
                wA + ((size_t)((wo * 3 + rr) * NQ + q) * 64 + lane) * 8);

        __syncthreads();   // also separates A1 writes on first iteration
#pragma unroll
        for (int it = 0; it < 4; it++) {
            const int kl = it * 8 + k7;
            const unsigned ck = q * 32 + kl;
            const unsigned c  = ck / 9u;
            const int kt = (int)(ck - c * 9u);
            const unsigned g = c / 48u;
            const int e = (((int)g * 9 + kt) << 6) + pp;
            const int exy = eXY[e];
            const int y0 = exy >> 16;
            const int x0 = (int)(short)(exy & 0xFFFF);
            const f32x4 w4 = eW4[e];
            const int yc0 = min(max(y0, 0), HH - 1);
            const int yc1 = min(max(y0 + 1, 0), HH - 1);
            const int xc0 = min(max(x0, 0), WW - 1);
            const int xc1 = min(max(x0 + 1, 0), WW - 1);
            const float* xb = x + ((size_t)(b * CC + c) << 14);
            const float v = w4[0] * xb[(yc0 << 7) + xc0] + w4[1] * xb[(yc0 << 7) + xc1]
                          + w4[2] * xb[(yc1 << 7) + xc0] + w4[3] * xb[(yc1 << 7) + xc1];
            SB[pp >> 4][(pp & 15) + 16 * it][k7] = f2bf(v);
        }
        __syncthreads();

        const short8 bF0 = *reinterpret_cast<const short8*>(&SB[wp * 2 + 0][lane][0]);
        const short8 bF1 = *reinterpret_cast<const short8*>(&SB[wp * 2 + 1][lane][0]);
#pragma unroll
        for (int rr = 0; rr < 3; rr++) {
            acc[rr][0] = __builtin_amdgcn_mfma_f32_16x16x32_bf16(aF[rr], bF0, acc[rr][0], 0, 0, 0);
            acc[rr][1] = __builtin_amdgcn_mfma_f32_16x16x32_bf16(aF[rr], bF1, acc[rr][1], 0, 0, 0);
        }
    }

    const int n0 = lane & 15;
    const int m4 = (lane >> 4) << 2;
#pragma unroll
    for (int rr = 0; rr < 3; rr++) {
#pragma unroll
        for (int nn = 0; nn < 2; nn++) {
            const int px = wp * 32 + nn * 16 + n0;
#pragma unroll
            for (int jr = 0; jr < 4; jr++) {
                const int o = (wo * 3 + rr) * 16 + m4 + jr;
                out[((size_t)(b * CC + o) << 14) + (i << 7) + j0 + px] = acc[rr][nn][jr] + bias[o];
            }
        }
    }
}

// ---------------------------------------------------------------------------
extern "C" void kernel_launch(void* const* d_in, const int* in_sizes, int n_in,
                              void* d_out, int out_size, void* d_ws, size_t ws_size,
                              hipStream_t stream)
{
    const float* x_vq  = (const float*)d_in[0];
    const float* x_res = (const float*)d_in[1];
    const float* w_off = (const float*)d_in[2];
    const float* b_off = (const float*)d_in[3];
    const float* w_co  = (const float*)d_in[4];
    const float* b_co  = (const float*)d_in[5];
    const float* w_dcn = (const float*)d_in[6];
    const float* b_dcn = (const float*)d_in[7];
    float* out = (float*)d_out;

    char* ws = (char*)d_ws;
    unsigned short* feat = (unsigned short*)ws;                 // bf16, 12.58 MB
    size_t feat_sz = (size_t)BB * CC * HW * 2;
    float* offb = (float*)(ws + feat_sz);                       // f32, 14.16 MB
    size_t offb_sz = (size_t)BB * 108 * HW * 4;
    short* wA1 = (short*)(ws + feat_sz + offb_sz);              // 12*108*512 elems
    short* wA2 = wA1 + (size_t)12 * 108 * 512;                  // 8*54*512 elems (mt 7 zero)
    short* wA3 = wA2 + (size_t)8 * 54 * 512;                    // 12*54*512 elems

    // weight packing
    {
        int tot1 = 12 * 108 * 64;
        pack_w_k<<<(tot1 + 255) / 256, 256, 0, stream>>>(w_off, wA1, 192, 3456, 12, 108);
        int tot2 = 8 * 54 * 64;
        pack_w_k<<<(tot2 + 255) / 256, 256, 0, stream>>>(w_co, wA2, 108, 1728, 8, 54);
        int tot3 = 12 * 54 * 64;
        pack_w_k<<<(tot3 + 255) / 256, 256, 0, stream>>>(w_dcn, wA3, 192, 1728, 12, 54);
    }

    dim3 grid(WW / 64, HH, BB);
    // conv1: concat(x_vq,x_res) [384] -> feat [192] bf16
    conv_mfma_k<3, true, float, unsigned short><<<grid, 512, 0, stream>>>(
        x_vq, x_res, wA1, b_off, feat, 384, 192, 108);
    // conv2: feat [192] bf16 -> offb [108] f32
    conv_mfma_k<2, false, unsigned short, float><<<grid, 512, 0, stream>>>(
        feat, (const unsigned short*)nullptr, wA2, b_co, offb, 192, 108, 54);
    // fused deform-sample + einsum
    dcn_mfma_k<<<grid, 512, 0, stream>>>(x_vq, offb, wA3, b_dcn, out);
}

// Round 3
// 448.034 us; speedup vs baseline: 6.4754x; 1.3850x over previous
//
#include <hip/hip_runtime.h>
#include <math.h>

#define HH 128
#define WW 128
#define HW 16384
#define BB 2
#define CC 192

typedef __attribute__((ext_vector_type(8))) short short8;
typedef __attribute__((ext_vector_type(4))) float f32x4;

// f32 -> bf16 bits, round-to-nearest-even
static __device__ __forceinline__ short f2bf(float f) {
    unsigned u = __float_as_uint(f);
    unsigned r = (u + 0x7FFFu + ((u >> 16) & 1u)) >> 16;
    return (short)r;
}

// ---------------------------------------------------------------------------
// Pack f32 weights into MFMA A-frag order.
// kgemm -> w[o*so + (kg/div)*s1 + (kg%div)*s2]; layout
// wp[((mt*NQ + chunk)*64 + lane)*8 + r], o = mt*16+(lane&15),
// kg = chunk*32 + (lane>>4)*8 + r. Zero-pad o >= Co.
// ---------------------------------------------------------------------------
__global__ void pack_w_k(const float* __restrict__ w, short* __restrict__ wp,
                         int Co, int Ktot, int MT, int div_, int s1, int s2, int so)
{
    int idx = blockIdx.x * blockDim.x + threadIdx.x;
    const int NQ = Ktot >> 5;
    const int total = MT * NQ * 64;
    if (idx >= total) return;
    const int l     = idx & 63;
    const int chunk = (idx >> 6) % NQ;
    const int mt    = (idx >> 6) / NQ;
    const int o     = mt * 16 + (l & 15);
    const int kg0   = chunk * 32 + ((l >> 4) << 3);
    short8 v;
#pragma unroll
    for (int r = 0; r < 8; r++) {
        const int kg = kg0 + r;
        float f = 0.f;
        if (o < Co) f = w[(size_t)o * so + (kg / div_) * s1 + (kg % div_) * s2];
        v[r] = f2bf(f);
    }
    *reinterpret_cast<short8*>(wp + (size_t)idx * 8) = v;
}

// ---------------------------------------------------------------------------
// 3x3 conv (pad 1) as implicit GEMM, channel-chunked staging + tap shifts.
// Block = 512 thr (8 waves), out tile [Cout<=MR*64][64 px] for one (b,row).
// LDS: X[3 rows][66 px][32 ch] bf16, CPAD=40 shorts (16B-aligned b128 reads).
// Wave (wo=wid>>1, wp=wid&1): m-tiles wo*MR.., n-tiles wp*2, wp*2+1.
// ---------------------------------------------------------------------------
#define CPAD 40
template<int MR, int NCH, bool CONCAT, typename InT, typename OutT>
__global__ __launch_bounds__(512) void conv_k(
    const InT* __restrict__ in0, const InT* __restrict__ in1,
    const short* __restrict__ wA, const float* __restrict__ bias,
    OutT* __restrict__ out, int Cout)
{
    __shared__ __align__(16) short X[3 * 66 * CPAD];

    const int t    = threadIdx.x;
    const int lane = t & 63;
    const int wid  = t >> 6;
    const int wo   = wid >> 1;
    const int wp   = wid & 1;
    const int j0   = blockIdx.x * 64;
    const int i    = blockIdx.y;
    const int b    = blockIdx.z;
    const int Cin  = NCH * 32;

    f32x4 acc[MR][2];
#pragma unroll
    for (int rr = 0; rr < MR; rr++) {
        acc[rr][0] = (f32x4){0.f, 0.f, 0.f, 0.f};
        acc[rr][1] = (f32x4){0.f, 0.f, 0.f, 0.f};
    }

    for (int qc = 0; qc < NCH; qc++) {
        __syncthreads();
        for (int idx = t; idx < 3 * 66 * 32; idx += 512) {
            const int rcn = idx / 66;        // row*32 + c
            const int px  = idx - rcn * 66;
            const int row = rcn >> 5;
            const int c   = rcn & 31;
            const int gy  = i - 1 + row;
            const int gx  = j0 - 1 + px;
            short bits = 0;
            if ((unsigned)gy < HH && (unsigned)gx < WW) {
                const int cg = qc * 32 + c;
                if constexpr (CONCAT) {
                    const int half = Cin / 2;
                    if (cg < half) bits = f2bf(in0[((size_t)(b * half + cg) << 14) + (gy << 7) + gx]);
                    else           bits = f2bf(in1[((size_t)(b * half + cg - half) << 14) + (gy << 7) + gx]);
                } else {
                    if constexpr (sizeof(InT) == 2)
                        bits = (short)in0[((size_t)(b * Cin + cg) << 14) + (gy << 7) + gx];
                    else
                        bits = f2bf((float)in0[((size_t)(b * Cin + cg) << 14) + (gy << 7) + gx]);
                }
            }
            X[(row * 66 + px) * CPAD + c] = bits;
        }
        __syncthreads();

#pragma unroll
        for (int tap = 0; tap < 9; tap++) {
            const int dy = tap / 3, dx = tap % 3;
            short8 aF[MR];
#pragma unroll
            for (int rr = 0; rr < MR; rr++)
                aF[rr] = *reinterpret_cast<const short8*>(
                    wA + ((size_t)((((wo * MR + rr) * 9 + tap) * NCH + qc) * 64 + lane)) * 8);
#pragma unroll
            for (int nn = 0; nn < 2; nn++) {
                const int pxi = (wp * 2 + nn) * 16 + (lane & 15) + dx;
                const short8 bF = *reinterpret_cast<const short8*>(
                    &X[(dy * 66 + pxi) * CPAD + ((lane >> 4) << 3)]);
#pragma unroll
                for (int rr = 0; rr < MR; rr++)
                    acc[rr][nn] = __builtin_amdgcn_mfma_f32_16x16x32_bf16(aF[rr], bF, acc[rr][nn], 0, 0, 0);
            }
        }
    }

    const int n0 = lane & 15;
    const int m4 = (lane >> 4) << 2;
#pragma unroll
    for (int rr = 0; rr < MR; rr++)
#pragma unroll
        for (int nn = 0; nn < 2; nn++) {
            const int px = (wp * 2 + nn) * 16 + n0;
#pragma unroll
            for (int jr = 0; jr < 4; jr++) {
                const int o = (wo * MR + rr) * 16 + m4 + jr;
                if (o < Cout) {
                    const float v = acc[rr][nn][jr] + bias[o];
                    if constexpr (sizeof(OutT) == 2)
                        out[((size_t)(b * Cout + o) << 14) + (i << 7) + j0 + px] = (OutT)f2bf(v);
                    else
                        out[((size_t)(b * Cout + o) << 14) + (i << 7) + j0 + px] = (OutT)v;
                }
            }
        }
}

// ---------------------------------------------------------------------------
// Fused deform-sample + einsum, private per-lane gather (no B staging, no
// K-loop barriers). Block = 256 thr (4 waves), out [192][64 px] per (b,i,j0).
// K-order kt-major: kgemm = kt*192 + c -> a lane's 8 slots share one entry
// (<=1 deform-group crossing). 2-deep ping-pong gather pipeline.
// ---------------------------------------------------------------------------
__global__ __launch_bounds__(256, 2) void dcn_k(
    const float* __restrict__ x, const float* __restrict__ off,
    const short* __restrict__ wA, const float* __restrict__ bias,
    float* __restrict__ out)
{
    __shared__ __align__(16) f32x4 eW[2304];   // 36 KB  (4*9 gk x 64 px)
    __shared__ __align__(8)  uint2 eO[2304];   // 18 KB  packed ushort4 offsets

    const int t    = threadIdx.x;
    const int lane = t & 63;
    const int wid  = t >> 6;       // 0..3 -> n-tile
    const int j0   = blockIdx.x * 64;
    const int i    = blockIdx.y;
    const int b    = blockIdx.z;

    // ---- A1: bilinear entries (identical math to verified round-2) ------
    for (int e = t; e < 2304; e += 256) {
        const int p  = e & 63;
        const int gk = e >> 6;               // g*9 + kt
        const int kt = gk % 9;
        const int j  = j0 + p;
        const size_t sp = (size_t)b * 108 * HW + (size_t)gk * HW + (i << 7) + j;
        const float dy = off[sp];
        const float dx = off[sp + (size_t)36 * HW];
        const float mv = off[sp + (size_t)72 * HW];
        const float m  = 1.f / (1.f + expf(-mv));
        const float py = (float)(i + kt / 3 - 1) + dy;
        const float px = (float)(j + kt % 3 - 1) + dx;
        const float y0f = floorf(py), x0f = floorf(px);
        const float ly = py - y0f, lx = px - x0f;
        const int y0 = (int)y0f, x0 = (int)x0f;
        const float vy0 = (y0 >= 0 && y0 < HH) ? 1.f : 0.f;
        const float vy1 = (y0 + 1 >= 0 && y0 + 1 < HH) ? 1.f : 0.f;
        const float vx0 = (x0 >= 0 && x0 < WW) ? 1.f : 0.f;
        const float vx1 = (x0 + 1 >= 0 && x0 + 1 < WW) ? 1.f : 0.f;
        f32x4 w4;
        w4[0] = (1.f - ly) * (1.f - lx) * m * vy0 * vx0;
        w4[1] = (1.f - ly) * lx         * m * vy0 * vx1;
        w4[2] = ly         * (1.f - lx) * m * vy1 * vx0;
        w4[3] = ly         * lx         * m * vy1 * vx1;
        const int yc0 = min(max(y0, 0), HH - 1);
        const int yc1 = min(max(y0 + 1, 0), HH - 1);
        const int xc0 = min(max(x0, 0), WW - 1);
        const int xc1 = min(max(x0 + 1, 0), WW - 1);
        const unsigned o00 = (unsigned)((yc0 << 7) + xc0);
        const unsigned o01 = (unsigned)((yc0 << 7) + xc1);
        const unsigned o10 = (unsigned)((yc1 << 7) + xc0);
        const unsigned o11 = (unsigned)((yc1 << 7) + xc1);
        eW[e] = w4;
        eO[e] = make_uint2(o00 | (o01 << 16), o10 | (o11 << 16));
    }
    __syncthreads();

    const int px_l  = (wid << 4) + (lane & 15);      // lane's pixel (0..63)
    const int slot8 = (lane >> 4) << 3;              // k-slot base
    const float* __restrict__ xu = x + ((size_t)(b * CC) << 14);

    f32x4 acc[12];
#pragma unroll
    for (int mt = 0; mt < 12; mt++) acc[mt] = (f32x4){0.f, 0.f, 0.f, 0.f};

#define DISSUE(Q, G, WL, WH, RC)                                              \
    {                                                                         \
        const int kt_ = (Q) / 6, cq_ = (Q) % 6;                               \
        const int cb_ = cq_ * 32 + slot8;                                     \
        const int gl_ = cb_ / 48, gh_ = (cb_ + 7) / 48;                       \
        const int el_ = gl_ * 576 + kt_ * 64 + px_l;                          \
        const int eh_ = gh_ * 576 + kt_ * 64 + px_l;                          \
        const uint2 ol_ = eO[el_];                                            \
        const uint2 oh_ = eO[eh_];                                            \
        WL = eW[el_]; WH = eW[eh_];                                           \
        RC = 48 - (cb_ - gl_ * 48);                                           \
        _Pragma("unroll")                                                     \
        for (int r = 0; r < 8; r++) {                                         \
            const uint2 oo = (r >= RC) ? oh_ : ol_;                           \
            const int base = (cb_ + r) << 14;                                 \
            G[r][0] = xu[base + (int)(oo.x & 0xFFFFu)];                       \
            G[r][1] = xu[base + (int)(oo.x >> 16)];                           \
            G[r][2] = xu[base + (int)(oo.y & 0xFFFFu)];                       \
            G[r][3] = xu[base + (int)(oo.y >> 16)];                           \
        }                                                                     \
    }

#define DCOMBINE(G, WL, WH, RC, BF)                                           \
    {                                                                         \
        _Pragma("unroll")                                                     \
        for (int r = 0; r < 8; r++) {                                         \
            const f32x4 wv = (r >= RC) ? WH : WL;                             \
            const float v = wv[0] * G[r][0] + wv[1] * G[r][1]                 \
                          + wv[2] * G[r][2] + wv[3] * G[r][3];                \
            BF[r] = f2bf(v);                                                  \
        }                                                                     \
    }

#define DALOAD(Q, AFV)                                                        \
    {                                                                         \
        _Pragma("unroll")                                                     \
        for (int mt = 0; mt < 12; mt++)                                       \
            AFV[mt] = *reinterpret_cast<const short8*>(                       \
                wA + ((size_t)((mt * 54 + (Q)) * 64 + lane)) * 8);            \
    }

    float G[8][4], H[8][4];
    f32x4 wlG, whG, wlH, whH;
    int rcG, rcH;

    DISSUE(0, G, wlG, whG, rcG);
    for (int q = 0; q < 54; q += 2) {
        short8 aFv[12];
        DISSUE(q + 1, H, wlH, whH, rcH);
        DALOAD(q, aFv);
        short8 bF;
        DCOMBINE(G, wlG, whG, rcG, bF);
#pragma unroll
        for (int mt = 0; mt < 12; mt++)
            acc[mt] = __builtin_amdgcn_mfma_f32_16x16x32_bf16(aFv[mt], bF, acc[mt], 0, 0, 0);

        if (q + 2 < 54) DISSUE(q + 2, G, wlG, whG, rcG);
        DALOAD(q + 1, aFv);
        short8 bF2;
        DCOMBINE(H, wlH, whH, rcH, bF2);
#pragma unroll
        for (int mt = 0; mt < 12; mt++)
            acc[mt] = __builtin_amdgcn_mfma_f32_16x16x32_bf16(aFv[mt], bF2, acc[mt], 0, 0, 0);
    }

    const int m4 = (lane >> 4) << 2;
#pragma unroll
    for (int mt = 0; mt < 12; mt++)
#pragma unroll
        for (int jr = 0; jr < 4; jr++) {
            const int o = mt * 16 + m4 + jr;
            out[((size_t)(b * CC + o) << 14) + (i << 7) + j0 + px_l] = acc[mt][jr] + bias[o];
        }
}

// ---------------------------------------------------------------------------
extern "C" void kernel_launch(void* const* d_in, const int* in_sizes, int n_in,
                              void* d_out, int out_size, void* d_ws, size_t ws_size,
                              hipStream_t stream)
{
    const float* x_vq  = (const float*)d_in[0];
    const float* x_res = (const float*)d_in[1];
    const float* w_off = (const float*)d_in[2];
    const float* b_off = (const float*)d_in[3];
    const float* w_co  = (const float*)d_in[4];
    const float* b_co  = (const float*)d_in[5];
    const float* w_dcn = (const float*)d_in[6];
    const float* b_dcn = (const float*)d_in[7];
    float* out = (float*)d_out;

    char* ws = (char*)d_ws;
    unsigned short* feat = (unsigned short*)ws;                 // bf16, 12.58 MB
    const size_t feat_sz = (size_t)BB * CC * HW * 2;
    float* offb = (float*)(ws + feat_sz);                       // f32, 14.16 MB
    const size_t offb_sz = (size_t)BB * 108 * HW * 4;
    short* wA1 = (short*)(ws + feat_sz + offb_sz);              // 12*108*512
    short* wA2 = wA1 + (size_t)12 * 108 * 512;                  // 8*54*512
    short* wA3 = wA2 + (size_t)8 * 54 * 512;                    // 12*54*512

    // packing: conv kgemm = tap*Cin + c ; dcn kgemm = kt*192 + c
    pack_w_k<<<(12 * 108 * 64 + 255) / 256, 256, 0, stream>>>(w_off, wA1, 192, 3456, 12, 384, 1, 9, 3456);
    pack_w_k<<<(8 * 54 * 64 + 255) / 256, 256, 0, stream>>>(w_co, wA2, 108, 1728, 8, 192, 1, 9, 1728);
    pack_w_k<<<(12 * 54 * 64 + 255) / 256, 256, 0, stream>>>(w_dcn, wA3, 192, 1728, 12, 192, 1, 9, 1728);

    dim3 grid(WW / 64, HH, BB);
    conv_k<3, 12, true, float, unsigned short><<<grid, 512, 0, stream>>>(
        x_vq, x_res, wA1, b_off, feat, 192);
    conv_k<2, 6, false, unsigned short, float><<<grid, 512, 0, stream>>>(
        feat, (const unsigned short*)nullptr, wA2, b_co, offb, 108);
    dcn_k<<<grid, 256, 0, stream>>>(x_vq, offb, wA3, b_dcn, out);
}